// Round 6
// baseline (311.518 us; speedup 1.0000x reference)
//
#include <hip/hip_runtime.h>
#include <math.h>

#define BATCH 8
#define T 1024
#define DM 512
#define NH 8
#define CHD 64
#define NROW 8192
#define NEG_INF (-INFINITY)
#define SENT (-1.0e30f)

typedef __attribute__((ext_vector_type(8))) short short8;   // 8 bf16 (4 VGPRs)
typedef __attribute__((ext_vector_type(4))) float f32x4;

__device__ __forceinline__ ushort f2bf(float x) {
  uint u = __float_as_uint(x);
  return (ushort)((u + 0x7FFFu + ((u >> 16) & 1u)) >> 16);
}
__device__ __forceinline__ uint pack2(float a, float b) {
  return (uint)f2bf(a) | ((uint)f2bf(b) << 16);
}

// ---------------------------------------------------------------- n_valid
__global__ __launch_bounds__(256) void k_nvalid(const int* __restrict__ tokens,
                                                int* __restrict__ nv) {
  int b = blockIdx.x, t = threadIdx.x;
  int cnt = 0;
  for (int i = t; i < T; i += 256) cnt += (tokens[b * T + i] != 0) ? 1 : 0;
  __shared__ int s[256];
  s[t] = cnt;
  __syncthreads();
  for (int st = 128; st > 0; st >>= 1) {
    if (t < st) s[t] += s[t + st];
    __syncthreads();
  }
  if (t == 0) nv[b] = s[0];
}

// ---------------------------------------------------------------- zero Sig
__global__ __launch_bounds__(256) void k_zero(float* __restrict__ Sig) {
  const int i = (blockIdx.x * 256 + threadIdx.x) * 4;
  *(float4*)(Sig + i) = (float4){0.f, 0.f, 0.f, 0.f};
}

// ---------------------------------------------------------------- W -> bf16 concat
__global__ __launch_bounds__(256) void k_prep_w(const float* __restrict__ Wq,
                                                const float* __restrict__ Wk,
                                                ushort* __restrict__ Wbf) {
  const int gid = blockIdx.x * 256 + threadIdx.x;
  const int e0 = gid * 8;
  const int n = e0 >> 10, k = e0 & 1023;
  const float* src = (n < 512) ? (Wq + (size_t)n * 1024 + k)
                               : (Wk + (size_t)(n - 512) * 1024 + k);
  float4 a = *(const float4*)src;
  float4 b = *(const float4*)(src + 4);
  uint4 o;
  o.x = pack2(a.x, a.y); o.y = pack2(a.z, a.w);
  o.z = pack2(b.x, b.y); o.w = pack2(b.z, b.w);
  *(uint4*)(Wbf + (size_t)n * 1024 + k) = o;
}

// ---------------------------------------------------------------- fused q/k GEMM (bf16 MFMA, XCD-swizzled)
__global__ __launch_bounds__(256) void k_gemm(
    const float* __restrict__ feat, const float* __restrict__ pos,
    const ushort* __restrict__ Wbf,
    const float* __restrict__ bq, const float* __restrict__ bk,
    ushort* __restrict__ qbuf, ushort* __restrict__ kbuf) {
  const int n = blockIdx.x;
  const int x = n & 7;
  const int lcl = n >> 3;
  const int nt = lcl >> 3;
  const int mt = x * 8 + (lcl & 7);
  const int n0 = nt * 128, m0 = mt * 128;
  const int tid = threadIdx.x;
  const int w = tid >> 6, l = tid & 63;
  const int lo = l & 15, quad = l >> 4;
  const int wm0 = (w >> 1) * 64, wn0 = (w & 1) * 64;

  __shared__ ushort As[128][72];
  __shared__ ushort Bs[128][72];

  f32x4 acc[4][4];
#pragma unroll
  for (int i = 0; i < 4; ++i)
#pragma unroll
    for (int j = 0; j < 4; ++j) acc[i][j] = (f32x4){0.f, 0.f, 0.f, 0.f};

  for (int k0 = 0; k0 < 1024; k0 += 64) {
    __syncthreads();
#pragma unroll
    for (int u = 0; u < 4; ++u) {
      const int cid = tid + 256 * u;
      const int r = cid >> 3, c = (cid & 7) * 8;
      const int gk = k0 + c;
      const float* src = (gk < 512) ? (feat + (size_t)(m0 + r) * 512 + gk)
                                    : (pos + (size_t)(m0 + r) * 512 + (gk - 512));
      float4 a = *(const float4*)src;
      float4 b = *(const float4*)(src + 4);
      uint4 o;
      o.x = pack2(a.x, a.y); o.y = pack2(a.z, a.w);
      o.z = pack2(b.x, b.y); o.w = pack2(b.z, b.w);
      *(uint4*)&As[r][c] = o;
    }
#pragma unroll
    for (int u = 0; u < 4; ++u) {
      const int cid = tid + 256 * u;
      const int r = cid >> 3, c = (cid & 7) * 8;
      *(uint4*)&Bs[r][c] = *(const uint4*)(Wbf + (size_t)(n0 + r) * 1024 + k0 + c);
    }
    __syncthreads();
#pragma unroll
    for (int kk = 0; kk < 2; ++kk) {
      short8 af[4], bf[4];
#pragma unroll
      for (int mi = 0; mi < 4; ++mi)
        af[mi] = *(const short8*)&As[wm0 + mi * 16 + lo][kk * 32 + quad * 8];
#pragma unroll
      for (int ni = 0; ni < 4; ++ni)
        bf[ni] = *(const short8*)&Bs[wn0 + ni * 16 + lo][kk * 32 + quad * 8];
#pragma unroll
      for (int mi = 0; mi < 4; ++mi)
#pragma unroll
        for (int ni = 0; ni < 4; ++ni)
          acc[mi][ni] = __builtin_amdgcn_mfma_f32_16x16x32_bf16(af[mi], bf[ni], acc[mi][ni], 0, 0, 0);
    }
  }

  float bv[4];
#pragma unroll
  for (int ni = 0; ni < 4; ++ni) {
    const int gn = n0 + wn0 + ni * 16 + lo;
    bv[ni] = (gn < 512) ? bq[gn] : bk[gn - 512];
  }
#pragma unroll
  for (int mi = 0; mi < 4; ++mi)
#pragma unroll
    for (int ni = 0; ni < 4; ++ni) {
      const int gn = n0 + wn0 + ni * 16 + lo;
      ushort* dst = (gn < 512) ? (qbuf + gn) : (kbuf + gn - 512);
#pragma unroll
      for (int r = 0; r < 4; ++r) {
        const int m = m0 + wm0 + mi * 16 + quad * 4 + r;
        dst[(size_t)m * 512] = f2bf(acc[mi][ni][r] + bv[ni]);
      }
    }
}

// ---------------------------------------------------------------- gates (wave per row, 4 rows/block)
__global__ __launch_bounds__(256) void k_gates(
    const float* __restrict__ feat, const float* __restrict__ pos,
    const float* __restrict__ Wg, const float* __restrict__ bg,
    float* __restrict__ gout) {
  const int row = blockIdx.x * 4 + (threadIdx.x >> 6);
  const int l = threadIdx.x & 63;
  const int c0 = l * 16;
  const float* src = (c0 < 512) ? (feat + (size_t)row * 512 + c0)
                                : (pos + (size_t)row * 512 + (c0 - 512));
  float4 f0 = *(const float4*)(src + 0);
  float4 f1 = *(const float4*)(src + 4);
  float4 f2 = *(const float4*)(src + 8);
  float4 f3 = *(const float4*)(src + 12);
  float s[8];
#pragma unroll
  for (int h = 0; h < 8; ++h) {
    const float* wg = Wg + (size_t)h * 1024 + c0;
    float4 w0 = *(const float4*)(wg + 0);
    float4 w1 = *(const float4*)(wg + 4);
    float4 w2 = *(const float4*)(wg + 8);
    float4 w3 = *(const float4*)(wg + 12);
    s[h] = f0.x * w0.x + f0.y * w0.y + f0.z * w0.z + f0.w * w0.w
         + f1.x * w1.x + f1.y * w1.y + f1.z * w1.z + f1.w * w1.w
         + f2.x * w2.x + f2.y * w2.y + f2.z * w2.z + f2.w * w2.w
         + f3.x * w3.x + f3.y * w3.y + f3.z * w3.z + f3.w * w3.w;
  }
#pragma unroll
  for (int m = 1; m < 64; m <<= 1)
#pragma unroll
    for (int h = 0; h < 8; ++h) s[h] += __shfl_xor(s[h], m, 64);
  if (l == 0) {
    float lg[8], mx = -1e30f;
#pragma unroll
    for (int h = 0; h < 8; ++h) { lg[h] = s[h] + bg[h]; mx = fmaxf(mx, lg[h]); }
    float sum = 0.f;
#pragma unroll
    for (int h = 0; h < 8; ++h) sum += __expf(lg[h] - mx);
    const float lse = mx + __logf(sum);
#pragma unroll
    for (int h = 0; h < 8; ++h) gout[(size_t)row * 8 + h] = lg[h] - lse;
  }
}

// ---------------------------------------------------------------- K-tile staging (8 KB: 64 rows x 64 ushort)
// LDS chunk swizzle: chunk' = (chunk + row) & 7 -> uniform banks for b128 r/w.
__device__ __forceinline__ void stage_k(ushort* __restrict__ dst,
                                        const ushort* __restrict__ src,
                                        int tid) {
  const int r = tid >> 2;        // 0..63
  const int s = (tid & 3) * 2;   // chunk 0,2,4,6
  const uint4 v0 = *(const uint4*)(src + (size_t)r * 512 + s * 8);
  const uint4 v1 = *(const uint4*)(src + (size_t)r * 512 + s * 8 + 8);
  *(uint4*)(dst + r * 64 + ((s + r) & 7) * 8) = v0;
  *(uint4*)(dst + r * 64 + ((s + 1 + r) & 7) * 8) = v1;
}
__device__ __forceinline__ short8 kfrag(const ushort* __restrict__ buf, int row, int ch) {
  return *(const short8*)(buf + row * 64 + ((ch + row) & 7) * 8);
}

// ---------------------------------------------------------------- pass1: Sig[b,i,h] += sum_j exp(q.k/8)
__global__ __launch_bounds__(256) void k_pass1(
    const ushort* __restrict__ q, const ushort* __restrict__ kk,
    const int* __restrict__ nvp, float* __restrict__ Sig) {
  const int jt = blockIdx.x, it = blockIdx.y, b = blockIdx.z;
  const int nv = nvp[b];
  const int i0 = it * 64, j0 = jt * 64;
  if (jt < it || j0 >= nv) return;
  const int tid = threadIdx.x;
  const int w = tid >> 6, l = tid & 63;
  const int lo = l & 15, quad = l >> 4;
  const int rm = i0 + w * 16;
  const bool edge = (it == jt) || (j0 + 64 > nv);

  __shared__ ushort Kb[2][64 * 64];

  const ushort* qrow = q + ((size_t)(b * T + rm + lo)) * 512 + quad * 8;
  const ushort* krow = kk + ((size_t)(b * T + j0)) * 512;

  stage_k(Kb[0], krow, tid);
  short8 qc0 = *(const short8*)(qrow);
  short8 qc1 = *(const short8*)(qrow + 32);

  float ls[8][4];
#pragma unroll
  for (int h = 0; h < 8; ++h)
#pragma unroll
    for (int r = 0; r < 4; ++r) ls[h][r] = 0.f;

  __syncthreads();
#pragma unroll
  for (int h = 0; h < 8; ++h) {
    short8 qn0 = qc0, qn1 = qc1;
    if (h < 7) {
      stage_k(Kb[(h + 1) & 1], krow + (h + 1) * 64, tid);
      qn0 = *(const short8*)(qrow + (h + 1) * 64);
      qn1 = *(const short8*)(qrow + (h + 1) * 64 + 32);
    }
    const ushort* cur = Kb[h & 1];
#pragma unroll
    for (int ni = 0; ni < 4; ++ni) {
      const short8 b0 = kfrag(cur, ni * 16 + lo, quad);
      const short8 b1 = kfrag(cur, ni * 16 + lo, 4 + quad);
      f32x4 acc = (f32x4){0.f, 0.f, 0.f, 0.f};
      acc = __builtin_amdgcn_mfma_f32_16x16x32_bf16(qc0, b0, acc, 0, 0, 0);
      acc = __builtin_amdgcn_mfma_f32_16x16x32_bf16(qc1, b1, acc, 0, 0, 0);
      if (!edge) {
#pragma unroll
        for (int r = 0; r < 4; ++r) ls[h][r] += __expf(acc[r] * 0.125f);
      } else {
        const int j = j0 + ni * 16 + lo;
#pragma unroll
        for (int r = 0; r < 4; ++r) {
          const int i = rm + quad * 4 + r;
          if (j > i && j < nv) ls[h][r] += __expf(acc[r] * 0.125f);
        }
      }
    }
    qc0 = qn0; qc1 = qn1;
    __syncthreads();
  }

#pragma unroll
  for (int h = 0; h < 8; ++h)
#pragma unroll
    for (int r = 0; r < 4; ++r) {
      float v = ls[h][r];
      v += __shfl_xor(v, 1, 64);
      v += __shfl_xor(v, 2, 64);
      v += __shfl_xor(v, 4, 64);
      v += __shfl_xor(v, 8, 64);
      if (lo == 0)
        atomicAdd(Sig + ((size_t)(b * T + rm + quad * 4 + r)) * 8 + h, v);
    }
}

// ---------------------------------------------------------------- pass2
__global__ __launch_bounds__(256) void k_pass2(
    const ushort* __restrict__ q, const ushort* __restrict__ kk,
    const float* __restrict__ g, const float* __restrict__ Sig,
    const int* __restrict__ nvp, float* __restrict__ out) {
  const int jt = blockIdx.x, it = blockIdx.y, b = blockIdx.z;
  const int nv = nvp[b];
  const int i0 = it * 64, j0 = jt * 64;
  const int tid = threadIdx.x;

  if (jt < it || j0 >= nv) {
    const int r0 = tid >> 4, c0 = (tid & 15) * 4;
    float4 v; v.x = v.y = v.z = v.w = SENT;
#pragma unroll
    for (int u = 0; u < 4; ++u)
      *(float4*)(out + ((size_t)(b * T + i0 + r0 + u * 16)) * T + j0 + c0) = v;
    return;
  }

  const int w = tid >> 6, l = tid & 63;
  const int lo = l & 15, quad = l >> 4;
  const int rm = i0 + w * 16;
  const int rbase = rm + quad * 4;

  __shared__ ushort Kb[2][64 * 64];

  const ushort* qrow = q + ((size_t)(b * T + rm + lo)) * 512 + quad * 8;
  const ushort* krow = kk + ((size_t)(b * T + j0)) * 512;
  const float* Sp = Sig + ((size_t)(b * T + rbase)) * 8;
  const float* gp = g + ((size_t)(b * T + rbase)) * 8;

  stage_k(Kb[0], krow, tid);
  short8 qc0 = *(const short8*)(qrow);
  short8 qc1 = *(const short8*)(qrow + 32);
  float wvc[4];
#pragma unroll
  for (int r = 0; r < 4; ++r) {
    const float sv = Sp[r * 8];
    wvc[r] = (sv > 0.f) ? (gp[r * 8] - __logf(sv)) : NEG_INF;
  }

  float se[4][4];  // [ni][r]
#pragma unroll
  for (int a = 0; a < 4; ++a)
#pragma unroll
    for (int c = 0; c < 4; ++c) se[a][c] = 0.f;

  __syncthreads();
#pragma unroll
  for (int h = 0; h < 8; ++h) {
    short8 qn0 = qc0, qn1 = qc1;
    float wvn[4] = {wvc[0], wvc[1], wvc[2], wvc[3]};
    if (h < 7) {
      stage_k(Kb[(h + 1) & 1], krow + (h + 1) * 64, tid);
      qn0 = *(const short8*)(qrow + (h + 1) * 64);
      qn1 = *(const short8*)(qrow + (h + 1) * 64 + 32);
#pragma unroll
      for (int r = 0; r < 4; ++r) {
        const float sv = Sp[r * 8 + h + 1];
        wvn[r] = (sv > 0.f) ? (gp[r * 8 + h + 1] - __logf(sv)) : NEG_INF;
      }
    }
    const ushort* cur = Kb[h & 1];
#pragma unroll
    for (int ni = 0; ni < 4; ++ni) {
      const short8 b0 = kfrag(cur, ni * 16 + lo, quad);
      const short8 b1 = kfrag(cur, ni * 16 + lo, 4 + quad);
      f32x4 acc = (f32x4){0.f, 0.f, 0.f, 0.f};
      acc = __builtin_amdgcn_mfma_f32_16x16x32_bf16(qc0, b0, acc, 0, 0, 0);
      acc = __builtin_amdgcn_mfma_f32_16x16x32_bf16(qc1, b1, acc, 0, 0, 0);
#pragma unroll
      for (int r = 0; r < 4; ++r) se[ni][r] += __expf(acc[r] * 0.125f + wvc[r]);
    }
    qc0 = qn0; qc1 = qn1;
    wvc[0] = wvn[0]; wvc[1] = wvn[1]; wvc[2] = wvn[2]; wvc[3] = wvn[3];
    __syncthreads();
  }

#pragma unroll
  for (int ni = 0; ni < 4; ++ni) {
    const int j = j0 + ni * 16 + lo;
#pragma unroll
    for (int r = 0; r < 4; ++r) {
      const int i = rbase + r;
      out[((size_t)(b * T + i)) * T + j] =
          (j > i && j < nv) ? fmaxf(__logf(se[ni][r]), SENT) : SENT;
    }
  }
}

// ---------------------------------------------------------------- launch
extern "C" void kernel_launch(void* const* d_in, const int* in_sizes, int n_in,
                              void* d_out, int out_size, void* d_ws, size_t ws_size,
                              hipStream_t stream) {
  (void)in_sizes; (void)n_in; (void)out_size; (void)ws_size;
  const float* feat = (const float*)d_in[0];
  const float* pos  = (const float*)d_in[1];
  const int* tokens = (const int*)d_in[2];
  const float* Wq = (const float*)d_in[3];
  const float* bq = (const float*)d_in[4];
  const float* Wk = (const float*)d_in[5];
  const float* bk = (const float*)d_in[6];
  const float* Wg = (const float*)d_in[7];
  const float* bg = (const float*)d_in[8];
  float* out = (float*)d_out;

  ushort* qbuf = (ushort*)d_ws;                         // 8192*512 bf16
  ushort* kbuf = qbuf + (size_t)NROW * 512;             // 8192*512 bf16
  ushort* Wbf  = kbuf + (size_t)NROW * 512;             // 1024*1024 bf16
  float*  gbuf = (float*)(Wbf + (size_t)1024 * 1024);   // 8192*8 f32
  float*  Sig  = gbuf + (size_t)NROW * NH;              // 8192*8 f32 accumulator
  int*    nv   = (int*)(Sig + (size_t)NROW * NH);

  k_nvalid<<<dim3(BATCH), dim3(256), 0, stream>>>(tokens, nv);
  k_zero<<<dim3(64), dim3(256), 0, stream>>>(Sig);
  k_prep_w<<<dim3(512), dim3(256), 0, stream>>>(Wq, Wk, Wbf);
  k_gemm<<<dim3(512), dim3(256), 0, stream>>>(feat, pos, Wbf, bq, bk, qbuf, kbuf);
  k_gates<<<dim3(NROW / 4), dim3(256), 0, stream>>>(feat, pos, Wg, bg, gbuf);
  k_pass1<<<dim3(16, 16, BATCH), dim3(256), 0, stream>>>(qbuf, kbuf, nv, Sig);
  k_pass2<<<dim3(16, 16, BATCH), dim3(256), 0, stream>>>(qbuf, kbuf, gbuf, Sig, nv, out);
}

// Round 7
// 239.744 us; speedup vs baseline: 1.2994x; 1.2994x over previous
//
#include <hip/hip_runtime.h>
#include <math.h>

#define BATCH 8
#define T 1024
#define DM 512
#define NH 8
#define CHD 64
#define NROW 8192
#define NEG_INF (-INFINITY)
#define SENT (-1.0e30f)

typedef __attribute__((ext_vector_type(8))) short short8;   // 8 bf16 (4 VGPRs)
typedef __attribute__((ext_vector_type(4))) float f32x4;

__device__ __forceinline__ ushort f2bf(float x) {
  uint u = __float_as_uint(x);
  return (ushort)((u + 0x7FFFu + ((u >> 16) & 1u)) >> 16);
}
__device__ __forceinline__ uint pack2(float a, float b) {
  return (uint)f2bf(a) | ((uint)f2bf(b) << 16);
}

// ---------------------------------------------------------------- n_valid
__global__ __launch_bounds__(256) void k_nvalid(const int* __restrict__ tokens,
                                                int* __restrict__ nv) {
  int b = blockIdx.x, t = threadIdx.x;
  int cnt = 0;
  for (int i = t; i < T; i += 256) cnt += (tokens[b * T + i] != 0) ? 1 : 0;
  __shared__ int s[256];
  s[t] = cnt;
  __syncthreads();
  for (int st = 128; st > 0; st >>= 1) {
    if (t < st) s[t] += s[t + st];
    __syncthreads();
  }
  if (t == 0) nv[b] = s[0];
}

// ---------------------------------------------------------------- zero Sig
__global__ __launch_bounds__(256) void k_zero(float* __restrict__ Sig) {
  const int i = (blockIdx.x * 256 + threadIdx.x) * 4;
  *(float4*)(Sig + i) = (float4){0.f, 0.f, 0.f, 0.f};
}

// ---------------------------------------------------------------- W -> bf16 concat
__global__ __launch_bounds__(256) void k_prep_w(const float* __restrict__ Wq,
                                                const float* __restrict__ Wk,
                                                ushort* __restrict__ Wbf) {
  const int gid = blockIdx.x * 256 + threadIdx.x;
  const int e0 = gid * 8;
  const int n = e0 >> 10, k = e0 & 1023;
  const float* src = (n < 512) ? (Wq + (size_t)n * 1024 + k)
                               : (Wk + (size_t)(n - 512) * 1024 + k);
  float4 a = *(const float4*)src;
  float4 b = *(const float4*)(src + 4);
  uint4 o;
  o.x = pack2(a.x, a.y); o.y = pack2(a.z, a.w);
  o.z = pack2(b.x, b.y); o.w = pack2(b.z, b.w);
  *(uint4*)(Wbf + (size_t)n * 1024 + k) = o;
}

// ---------------------------------------------------------------- fused q/k GEMM (bf16 MFMA, XCD-swizzled)
__global__ __launch_bounds__(256) void k_gemm(
    const float* __restrict__ feat, const float* __restrict__ pos,
    const ushort* __restrict__ Wbf,
    const float* __restrict__ bq, const float* __restrict__ bk,
    ushort* __restrict__ qbuf, ushort* __restrict__ kbuf) {
  const int n = blockIdx.x;
  const int x = n & 7;
  const int lcl = n >> 3;
  const int nt = lcl >> 3;
  const int mt = x * 8 + (lcl & 7);
  const int n0 = nt * 128, m0 = mt * 128;
  const int tid = threadIdx.x;
  const int w = tid >> 6, l = tid & 63;
  const int lo = l & 15, quad = l >> 4;
  const int wm0 = (w >> 1) * 64, wn0 = (w & 1) * 64;

  __shared__ ushort As[128][72];
  __shared__ ushort Bs[128][72];

  f32x4 acc[4][4];
#pragma unroll
  for (int i = 0; i < 4; ++i)
#pragma unroll
    for (int j = 0; j < 4; ++j) acc[i][j] = (f32x4){0.f, 0.f, 0.f, 0.f};

  for (int k0 = 0; k0 < 1024; k0 += 64) {
    __syncthreads();
#pragma unroll
    for (int u = 0; u < 4; ++u) {
      const int cid = tid + 256 * u;
      const int r = cid >> 3, c = (cid & 7) * 8;
      const int gk = k0 + c;
      const float* src = (gk < 512) ? (feat + (size_t)(m0 + r) * 512 + gk)
                                    : (pos + (size_t)(m0 + r) * 512 + (gk - 512));
      float4 a = *(const float4*)src;
      float4 b = *(const float4*)(src + 4);
      uint4 o;
      o.x = pack2(a.x, a.y); o.y = pack2(a.z, a.w);
      o.z = pack2(b.x, b.y); o.w = pack2(b.z, b.w);
      *(uint4*)&As[r][c] = o;
    }
#pragma unroll
    for (int u = 0; u < 4; ++u) {
      const int cid = tid + 256 * u;
      const int r = cid >> 3, c = (cid & 7) * 8;
      *(uint4*)&Bs[r][c] = *(const uint4*)(Wbf + (size_t)(n0 + r) * 1024 + k0 + c);
    }
    __syncthreads();
#pragma unroll
    for (int kk = 0; kk < 2; ++kk) {
      short8 af[4], bf[4];
#pragma unroll
      for (int mi = 0; mi < 4; ++mi)
        af[mi] = *(const short8*)&As[wm0 + mi * 16 + lo][kk * 32 + quad * 8];
#pragma unroll
      for (int ni = 0; ni < 4; ++ni)
        bf[ni] = *(const short8*)&Bs[wn0 + ni * 16 + lo][kk * 32 + quad * 8];
#pragma unroll
      for (int mi = 0; mi < 4; ++mi)
#pragma unroll
        for (int ni = 0; ni < 4; ++ni)
          acc[mi][ni] = __builtin_amdgcn_mfma_f32_16x16x32_bf16(af[mi], bf[ni], acc[mi][ni], 0, 0, 0);
    }
  }

  float bv[4];
#pragma unroll
  for (int ni = 0; ni < 4; ++ni) {
    const int gn = n0 + wn0 + ni * 16 + lo;
    bv[ni] = (gn < 512) ? bq[gn] : bk[gn - 512];
  }
#pragma unroll
  for (int mi = 0; mi < 4; ++mi)
#pragma unroll
    for (int ni = 0; ni < 4; ++ni) {
      const int gn = n0 + wn0 + ni * 16 + lo;
      ushort* dst = (gn < 512) ? (qbuf + gn) : (kbuf + gn - 512);
#pragma unroll
      for (int r = 0; r < 4; ++r) {
        const int m = m0 + wm0 + mi * 16 + quad * 4 + r;
        dst[(size_t)m * 512] = f2bf(acc[mi][ni][r] + bv[ni]);
      }
    }
}

// ---------------------------------------------------------------- gates (wave per row, 4 rows/block)
__global__ __launch_bounds__(256) void k_gates(
    const float* __restrict__ feat, const float* __restrict__ pos,
    const float* __restrict__ Wg, const float* __restrict__ bg,
    float* __restrict__ gout) {
  const int row = blockIdx.x * 4 + (threadIdx.x >> 6);
  const int l = threadIdx.x & 63;
  const int c0 = l * 16;
  const float* src = (c0 < 512) ? (feat + (size_t)row * 512 + c0)
                                : (pos + (size_t)row * 512 + (c0 - 512));
  float4 f0 = *(const float4*)(src + 0);
  float4 f1 = *(const float4*)(src + 4);
  float4 f2 = *(const float4*)(src + 8);
  float4 f3 = *(const float4*)(src + 12);
  float s[8];
#pragma unroll
  for (int h = 0; h < 8; ++h) {
    const float* wg = Wg + (size_t)h * 1024 + c0;
    float4 w0 = *(const float4*)(wg + 0);
    float4 w1 = *(const float4*)(wg + 4);
    float4 w2 = *(const float4*)(wg + 8);
    float4 w3 = *(const float4*)(wg + 12);
    s[h] = f0.x * w0.x + f0.y * w0.y + f0.z * w0.z + f0.w * w0.w
         + f1.x * w1.x + f1.y * w1.y + f1.z * w1.z + f1.w * w1.w
         + f2.x * w2.x + f2.y * w2.y + f2.z * w2.z + f2.w * w2.w
         + f3.x * w3.x + f3.y * w3.y + f3.z * w3.z + f3.w * w3.w;
  }
#pragma unroll
  for (int m = 1; m < 64; m <<= 1)
#pragma unroll
    for (int h = 0; h < 8; ++h) s[h] += __shfl_xor(s[h], m, 64);
  if (l == 0) {
    float lg[8], mx = -1e30f;
#pragma unroll
    for (int h = 0; h < 8; ++h) { lg[h] = s[h] + bg[h]; mx = fmaxf(mx, lg[h]); }
    float sum = 0.f;
#pragma unroll
    for (int h = 0; h < 8; ++h) sum += __expf(lg[h] - mx);
    const float lse = mx + __logf(sum);
#pragma unroll
    for (int h = 0; h < 8; ++h) gout[(size_t)row * 8 + h] = lg[h] - lse;
  }
}

// ================================================================ pass kernels
// Block tile: 64 i x 128 j. 4 waves: wave (hw,jw) computes 32i x 64j via
// 2x4 accs of the verified 16x16x32 bf16 MFMA. LDS: Qs 64x64 + Ks 128x64
// per head (staged each head, 2 barriers) -> 6 KB LDS-read per 1024 outputs.

// ---------------------------------------------------------------- pass1: Sig[b,i,h] += sum_j exp(q.k/8)
__global__ __launch_bounds__(256) void k_pass1(
    const ushort* __restrict__ q, const ushort* __restrict__ kk,
    const int* __restrict__ nvp, float* __restrict__ Sig) {
  const int jt = blockIdx.x;   // 0..7  (j0 = jt*128)
  const int it = blockIdx.y;   // 0..15 (i0 = it*64)
  const int b = blockIdx.z;
  const int nv = nvp[b];
  const int i0 = it * 64, j0 = jt * 128;
  if (j0 + 127 <= i0 || j0 >= nv) return;
  const int tid = threadIdx.x;
  const int w = tid >> 6, l = tid & 63;
  const int lo = l & 15, quad = l >> 4;
  const int hw = w >> 1, jw = w & 1;
  const bool needmask = (j0 <= i0 + 63) || (j0 + 128 > nv);

  __shared__ ushort Qs[64][72];
  __shared__ ushort Ks[128][72];

  const size_t qbase = ((size_t)(b * T + i0)) * 512;
  const size_t kbase = ((size_t)(b * T + j0)) * 512;

  for (int h = 0; h < 8; ++h) {
    __syncthreads();
    // stage Q 64x64 (2 b128/thread)
#pragma unroll
    for (int u = 0; u < 2; ++u) {
      const int cid = tid + 256 * u;
      const int r = cid >> 3, c = (cid & 7) * 8;
      *(uint4*)&Qs[r][c] = *(const uint4*)(q + qbase + (size_t)r * 512 + h * 64 + c);
    }
    // stage K 128x64 (4 b128/thread)
#pragma unroll
    for (int u = 0; u < 4; ++u) {
      const int cid = tid + 256 * u;
      const int r = cid >> 3, c = (cid & 7) * 8;
      *(uint4*)&Ks[r][c] = *(const uint4*)(kk + kbase + (size_t)r * 512 + h * 64 + c);
    }
    __syncthreads();

    short8 a0[2], a1[2];
#pragma unroll
    for (int mi = 0; mi < 2; ++mi) {
      a0[mi] = *(const short8*)&Qs[hw * 32 + mi * 16 + lo][quad * 8];
      a1[mi] = *(const short8*)&Qs[hw * 32 + mi * 16 + lo][32 + quad * 8];
    }
    float lsum[2][4] = {{0.f, 0.f, 0.f, 0.f}, {0.f, 0.f, 0.f, 0.f}};
#pragma unroll
    for (int ni = 0; ni < 4; ++ni) {
      const short8 b0 = *(const short8*)&Ks[jw * 64 + ni * 16 + lo][quad * 8];
      const short8 b1 = *(const short8*)&Ks[jw * 64 + ni * 16 + lo][32 + quad * 8];
#pragma unroll
      for (int mi = 0; mi < 2; ++mi) {
        f32x4 acc = (f32x4){0.f, 0.f, 0.f, 0.f};
        acc = __builtin_amdgcn_mfma_f32_16x16x32_bf16(a0[mi], b0, acc, 0, 0, 0);
        acc = __builtin_amdgcn_mfma_f32_16x16x32_bf16(a1[mi], b1, acc, 0, 0, 0);
        if (!needmask) {
#pragma unroll
          for (int r = 0; r < 4; ++r) lsum[mi][r] += __expf(acc[r] * 0.125f);
        } else {
          const int j = j0 + jw * 64 + ni * 16 + lo;
#pragma unroll
          for (int r = 0; r < 4; ++r) {
            const int i = i0 + hw * 32 + mi * 16 + quad * 4 + r;
            if (j > i && j < nv) lsum[mi][r] += __expf(acc[r] * 0.125f);
          }
        }
      }
    }
    // reduce over the 16 lanes (j within wave) and accumulate
#pragma unroll
    for (int mi = 0; mi < 2; ++mi)
#pragma unroll
      for (int r = 0; r < 4; ++r) {
        float v = lsum[mi][r];
        v += __shfl_xor(v, 1, 64);
        v += __shfl_xor(v, 2, 64);
        v += __shfl_xor(v, 4, 64);
        v += __shfl_xor(v, 8, 64);
        if (lo == 0) {
          const int i = i0 + hw * 32 + mi * 16 + quad * 4 + r;
          atomicAdd(Sig + ((size_t)(b * T + i)) * 8 + h, v);
        }
      }
  }
}

// ---------------------------------------------------------------- pass2
__global__ __launch_bounds__(256) void k_pass2(
    const ushort* __restrict__ q, const ushort* __restrict__ kk,
    const float* __restrict__ g, const float* __restrict__ Sig,
    const int* __restrict__ nvp, float* __restrict__ out) {
  const int jt = blockIdx.x;   // 0..7
  const int it = blockIdx.y;   // 0..15
  const int b = blockIdx.z;
  const int nv = nvp[b];
  const int i0 = it * 64, j0 = jt * 128;
  const int tid = threadIdx.x;

  if (j0 + 127 <= i0 || j0 >= nv) {  // fully invalid tile -> sentinel
    float4 v; v.x = v.y = v.z = v.w = SENT;
#pragma unroll
    for (int u = 0; u < 8; ++u) {
      const int cid = tid + 256 * u;
      const int r = cid >> 5, c4 = (cid & 31) * 4;
      *(float4*)(out + ((size_t)(b * T + i0 + r)) * T + j0 + c4) = v;
    }
    return;
  }

  const int w = tid >> 6, l = tid & 63;
  const int lo = l & 15, quad = l >> 4;
  const int hw = w >> 1, jw = w & 1;

  __shared__ ushort Qs[64][72];
  __shared__ ushort Ks[128][72];
  __shared__ float wsh[8][64];

  if (tid < 64) {
    const size_t rowg = ((size_t)(b * T + i0 + tid)) * 8;
#pragma unroll
    for (int h = 0; h < 8; ++h) {
      const float sv = Sig[rowg + h];
      wsh[h][tid] = (sv > 0.f) ? (g[rowg + h] - __logf(sv)) : NEG_INF;
    }
  }

  const size_t qbase = ((size_t)(b * T + i0)) * 512;
  const size_t kbase = ((size_t)(b * T + j0)) * 512;

  float se[2][4][4];
#pragma unroll
  for (int mi = 0; mi < 2; ++mi)
#pragma unroll
    for (int ni = 0; ni < 4; ++ni)
#pragma unroll
      for (int r = 0; r < 4; ++r) se[mi][ni][r] = 0.f;

  for (int h = 0; h < 8; ++h) {
    __syncthreads();
#pragma unroll
    for (int u = 0; u < 2; ++u) {
      const int cid = tid + 256 * u;
      const int r = cid >> 3, c = (cid & 7) * 8;
      *(uint4*)&Qs[r][c] = *(const uint4*)(q + qbase + (size_t)r * 512 + h * 64 + c);
    }
#pragma unroll
    for (int u = 0; u < 4; ++u) {
      const int cid = tid + 256 * u;
      const int r = cid >> 3, c = (cid & 7) * 8;
      *(uint4*)&Ks[r][c] = *(const uint4*)(kk + kbase + (size_t)r * 512 + h * 64 + c);
    }
    __syncthreads();

    short8 a0[2], a1[2];
    float wv[2][4];
#pragma unroll
    for (int mi = 0; mi < 2; ++mi) {
      a0[mi] = *(const short8*)&Qs[hw * 32 + mi * 16 + lo][quad * 8];
      a1[mi] = *(const short8*)&Qs[hw * 32 + mi * 16 + lo][32 + quad * 8];
#pragma unroll
      for (int r = 0; r < 4; ++r) wv[mi][r] = wsh[h][hw * 32 + mi * 16 + quad * 4 + r];
    }
#pragma unroll
    for (int ni = 0; ni < 4; ++ni) {
      const short8 b0 = *(const short8*)&Ks[jw * 64 + ni * 16 + lo][quad * 8];
      const short8 b1 = *(const short8*)&Ks[jw * 64 + ni * 16 + lo][32 + quad * 8];
#pragma unroll
      for (int mi = 0; mi < 2; ++mi) {
        f32x4 acc = (f32x4){0.f, 0.f, 0.f, 0.f};
        acc = __builtin_amdgcn_mfma_f32_16x16x32_bf16(a0[mi], b0, acc, 0, 0, 0);
        acc = __builtin_amdgcn_mfma_f32_16x16x32_bf16(a1[mi], b1, acc, 0, 0, 0);
#pragma unroll
        for (int r = 0; r < 4; ++r) se[mi][ni][r] += __expf(acc[r] * 0.125f + wv[mi][r]);
      }
    }
  }

#pragma unroll
  for (int mi = 0; mi < 2; ++mi)
#pragma unroll
    for (int ni = 0; ni < 4; ++ni) {
      const int j = j0 + jw * 64 + ni * 16 + lo;
#pragma unroll
      for (int r = 0; r < 4; ++r) {
        const int i = i0 + hw * 32 + mi * 16 + quad * 4 + r;
        out[((size_t)(b * T + i)) * T + j] =
            (j > i && j < nv) ? fmaxf(__logf(se[mi][ni][r]), SENT) : SENT;
      }
    }
}

// ---------------------------------------------------------------- launch
extern "C" void kernel_launch(void* const* d_in, const int* in_sizes, int n_in,
                              void* d_out, int out_size, void* d_ws, size_t ws_size,
                              hipStream_t stream) {
  (void)in_sizes; (void)n_in; (void)out_size; (void)ws_size;
  const float* feat = (const float*)d_in[0];
  const float* pos  = (const float*)d_in[1];
  const int* tokens = (const int*)d_in[2];
  const float* Wq = (const float*)d_in[3];
  const float* bq = (const float*)d_in[4];
  const float* Wk = (const float*)d_in[5];
  const float* bk = (const float*)d_in[6];
  const float* Wg = (const float*)d_in[7];
  const float* bg = (const float*)d_in[8];
  float* out = (float*)d_out;

  ushort* qbuf = (ushort*)d_ws;                         // 8192*512 bf16
  ushort* kbuf = qbuf + (size_t)NROW * 512;             // 8192*512 bf16
  ushort* Wbf  = kbuf + (size_t)NROW * 512;             // 1024*1024 bf16
  float*  gbuf = (float*)(Wbf + (size_t)1024 * 1024);   // 8192*8 f32
  float*  Sig  = gbuf + (size_t)NROW * NH;              // 8192*8 f32 accumulator
  int*    nv   = (int*)(Sig + (size_t)NROW * NH);

  k_nvalid<<<dim3(BATCH), dim3(256), 0, stream>>>(tokens, nv);
  k_zero<<<dim3(64), dim3(256), 0, stream>>>(Sig);
  k_prep_w<<<dim3(512), dim3(256), 0, stream>>>(Wq, Wk, Wbf);
  k_gemm<<<dim3(512), dim3(256), 0, stream>>>(feat, pos, Wbf, bq, bk, qbuf, kbuf);
  k_gates<<<dim3(NROW / 4), dim3(256), 0, stream>>>(feat, pos, Wg, bg, gbuf);
  k_pass1<<<dim3(8, 16, BATCH), dim3(256), 0, stream>>>(qbuf, kbuf, nv, Sig);
  k_pass2<<<dim3(8, 16, BATCH), dim3(256), 0, stream>>>(qbuf, kbuf, gbuf, Sig, nv, out);
}